// Round 12
// baseline (90.798 us; speedup 1.0000x reference)
//
#include <hip/hip_runtime.h>
#include <math.h>

// Hausdorff distance, B=16, N=4096, D=3, fp32.
// out[b] = 0.5*(max_gt min_pred d + max_pred min_gt d), d = ||p-q||^2
//
// R12. Known fixed cost (R11 discovery): harness re-poisons the 256MB
// d_ws at ~40us/iter (fillBufferAligned @84% HBM peak) + ~10us tail =>
// ~51us scaffold floor that no kernel change can touch. Optimizing the
// scan toward its pipe floors:
//  - SPLIT=4 (OPP=1024, LDS 33KB) -> 4 blocks/CU = 4 waves/SIMD
//    (R11's 65KB LDS capped at 2 -> latency-exposed chain).
//  - tile-PAIR unroll + v_min3_f32: two bfrags/iter, best = min3(best,
//    Da,Db) halves min-instruction count (VALU 6.8 -> 3.4us); per 4
//    MFMAs only 64 VALU-cyc -> matrix pipe (6.9us total) is binding.
//  - 2 independent MFMA streams/wave (HPW=64) unchanged; DPP row_ror
//    col-min epilogue (VALU) + single ds_swizzle cross unchanged.
// Budget: MFMA 6.9, LDS ~7, VALU ~4.5 overlapped at 4 waves/SIMD ->
// scan ~12-16us; total ~68-74us.
//
// Formulation (v_mfma_f32_32x32x16_f16): d(m,n)=hg[m]+(hp[n]-2g_m.p_n),
// f16 hi/lo split: k0..2 (-2g_hi)(p_hi), k3..5 (-2g_hi)(p_lo),
// k6..8 (-2g_lo)(p_hi), k9..10 1*hp_{hi,lo}; hg added in fp32 at end.
// C/D (m74/m101, R9..R11-validated): col=lane&31,
// row=(reg&3)+8*(reg>>2)+4*(lane>>5).

#define NPTS 4096
#define NB 16
#define TPB 256
#define WAVES 4
#define HPW 64                    // homes per wave (2 MFMA streams)
#define HPB (WAVES * HPW)         // 256 homes per block
#define NHB (NPTS / HPB)          // 16 home blocks
#define SPLIT 4
#define OPP (NPTS / SPLIT)        // 1024 opponents staged per block
#define TILES (OPP / 32)          // 32 bfrag tiles per wave

#define WSMIN_N (2 * NB * NPTS)

typedef _Float16 h8 __attribute__((ext_vector_type(8)));
typedef float f16v __attribute__((ext_vector_type(16)));

// min with DPP row_ror:N (VALU pipe; rows of 16 lanes, cyclic rotate)
template <int CTRL>
__device__ __forceinline__ float min_dpp(float v) {
    int s = __builtin_amdgcn_update_dpp(0, __float_as_int(v), CTRL, 0xF, 0xF, true);
    return fminf(v, __int_as_float(s));
}

__global__ __launch_bounds__(TPB) void haus_scan_kernel(
        const float* __restrict__ preds, const float* __restrict__ gts,
        unsigned int* __restrict__ wsmin) {
    const int hb  = blockIdx.x & (NHB - 1);
    const int sp  = blockIdx.x >> 4;          // NHB == 16
    const int b   = blockIdx.y;
    const int dir = blockIdx.z;               // 0: home=gts vs preds; 1: home=preds vs gts
    const int t   = threadIdx.x;
    const int lane = t & 63, w = t >> 6;
    const int l31 = lane & 31, half = lane >> 5;

    const float* home = (dir == 0) ? gts : preds;
    const float* opp  = (dir == 0) ? preds : gts;
    const float* hbp = home + (size_t)b * NPTS * 3;
    const float* obp = opp  + (size_t)b * NPTS * 3;

    __shared__ h8 srec[2 * OPP];              // [khalf][point] B-form records (32KB)
    __shared__ float shg[WAVES][HPW];

    // ---- stage opponents: B-form hi/lo records (full |p|^2) ----
#pragma unroll
    for (int i = 0; i < OPP / TPB; ++i) {
        int p = i * TPB + t;
        const float* s = obp + (size_t)(sp * OPP + p) * 3;
        float x = s[0], y = s[1], z = s[2];
        float hp = fmaf(x, x, fmaf(y, y, z * z));
        _Float16 xh = (_Float16)x, yh = (_Float16)y, zh = (_Float16)z;
        _Float16 xl = (_Float16)(x - (float)xh);
        _Float16 yl = (_Float16)(y - (float)yh);
        _Float16 zl = (_Float16)(z - (float)zh);
        _Float16 hph = (_Float16)hp, hpl = (_Float16)(hp - (float)hph);
        h8 lo, hi;
        lo[0] = xh; lo[1] = yh; lo[2] = zh;       // k0..2: p_hi
        lo[3] = xl; lo[4] = yl; lo[5] = zl;       // k3..5: p_lo
        lo[6] = xh; lo[7] = yh;                   // k6..7: p_hi (x,y)
        hi[0] = zh;                               // k8: p_hi z
        hi[1] = hph; hi[2] = hpl;                 // k9..10: hp split
        hi[3] = (_Float16)0; hi[4] = (_Float16)0;
        hi[5] = (_Float16)0; hi[6] = (_Float16)0; hi[7] = (_Float16)0;
        srec[p] = lo;
        srec[OPP + p] = hi;
    }

    // ---- A-frags: two streams of 32 homes, -2 * hi/lo split ----
    h8 afrag[2];
#pragma unroll
    for (int a = 0; a < 2; ++a) {
        int m = hb * HPB + w * HPW + a * 32 + l31;
        float gx = hbp[m * 3 + 0], gy = hbp[m * 3 + 1], gz = hbp[m * 3 + 2];
        float hg = fmaf(gx, gx, fmaf(gy, gy, gz * gz));
        shg[w][a * 32 + l31] = hg;            // both lane-halves write same value
        _Float16 gxh = (_Float16)gx, gyh = (_Float16)gy, gzh = (_Float16)gz;
        _Float16 gxl = (_Float16)(gx - (float)gxh);
        _Float16 gyl = (_Float16)(gy - (float)gyh);
        _Float16 gzl = (_Float16)(gz - (float)gzh);
        const _Float16 n2 = (_Float16)(-2.0f);
        h8 f;
        if (half == 0) {                      // k0..7
            f[0] = n2 * gxh; f[1] = n2 * gyh; f[2] = n2 * gzh;
            f[3] = n2 * gxh; f[4] = n2 * gyh; f[5] = n2 * gzh;
            f[6] = n2 * gxl; f[7] = n2 * gyl;
        } else {                              // k8..15
            f[0] = n2 * gzl;
            f[1] = (_Float16)1; f[2] = (_Float16)1;
            f[3] = (_Float16)0; f[4] = (_Float16)0;
            f[5] = (_Float16)0; f[6] = (_Float16)0; f[7] = (_Float16)0;
        }
        afrag[a] = f;
    }

    f16v zc = {};                             // zero C
    float best0[16], best1[16];
#pragma unroll
    for (int r = 0; r < 16; ++r) { best0[r] = INFINITY; best1[r] = INFINITY; }

    __syncthreads();

    const int base = half * OPP + l31;        // srec index for this lane
#pragma unroll 2
    for (int tt = 0; tt < TILES / 2; ++tt) {  // TWO tiles per iteration
        h8 bf0 = srec[base + (2 * tt) * 32];
        h8 bf1 = srec[base + (2 * tt + 1) * 32];
        f16v D0a = __builtin_amdgcn_mfma_f32_32x32x16_f16(afrag[0], bf0, zc, 0, 0, 0);
        f16v D0b = __builtin_amdgcn_mfma_f32_32x32x16_f16(afrag[0], bf1, zc, 0, 0, 0);
        f16v D1a = __builtin_amdgcn_mfma_f32_32x32x16_f16(afrag[1], bf0, zc, 0, 0, 0);
        f16v D1b = __builtin_amdgcn_mfma_f32_32x32x16_f16(afrag[1], bf1, zc, 0, 0, 0);
#pragma unroll
        for (int r = 0; r < 16; ++r)          // v_min3_f32 pattern
            best0[r] = fminf(fminf(best0[r], D0a[r]), D0b[r]);
#pragma unroll
        for (int r = 0; r < 16; ++r)
            best1[r] = fminf(fminf(best1[r], D1a[r]), D1b[r]);
    }

    // ---- min over 32 cols ----
    // steps 1,2,4,8: DPP row_ror rotations within 16-lane rows (VALU pipe)
#pragma unroll
    for (int r = 0; r < 16; ++r) {
        float a0 = best0[r], a1 = best1[r];
        a0 = min_dpp<0x121>(a0); a1 = min_dpp<0x121>(a1);   // ror 1
        a0 = min_dpp<0x122>(a0); a1 = min_dpp<0x122>(a1);   // ror 2
        a0 = min_dpp<0x124>(a0); a1 = min_dpp<0x124>(a1);   // ror 4
        a0 = min_dpp<0x128>(a0); a1 = min_dpp<0x128>(a1);   // ror 8
        // final step: cross the two 16-lane rows within each 32-half
        float s0 = __int_as_float(__builtin_amdgcn_ds_swizzle(__float_as_int(a0), 0x401F));
        float s1 = __int_as_float(__builtin_amdgcn_ds_swizzle(__float_as_int(a1), 0x401F));
        best0[r] = fminf(a0, s0);
        best1[r] = fminf(a1, s1);
    }

    unsigned int* slot = wsmin + ((size_t)dir * NB + b) * NPTS + hb * HPB + w * HPW;
    if (l31 == 0) {                           // lanes 0 and 32: disjoint row sets
#pragma unroll
        for (int r = 0; r < 16; ++r) {
            int row = (r & 3) + 8 * (r >> 2) + 4 * half;
            float d0 = fmaxf(best0[r] + shg[w][row], 0.0f);
            float d1 = fmaxf(best1[r] + shg[w][32 + row], 0.0f);
            atomicMin(slot + row, __float_as_uint(d0));
            atomicMin(slot + 32 + row, __float_as_uint(d1));
        }
    }
}

__global__ __launch_bounds__(TPB) void haus_final_kernel(
        const unsigned int* __restrict__ wsmin, float* __restrict__ out) {
    const int b = blockIdx.x;
    const int t = threadIdx.x;
    const float4* w0 = (const float4*)(wsmin + ((size_t)0 * NB + b) * NPTS);
    const float4* w1 = (const float4*)(wsmin + ((size_t)1 * NB + b) * NPTS);
    float m1 = -INFINITY, m2 = -INFINITY;
#pragma unroll
    for (int r = 0; r < NPTS / 4 / TPB; ++r) {   // 4 float4 per thread
        float4 a = w0[r * TPB + t];
        float4 c = w1[r * TPB + t];
        m1 = fmaxf(fmaxf(fmaxf(a.x, a.y), fmaxf(a.z, a.w)), m1);
        m2 = fmaxf(fmaxf(fmaxf(c.x, c.y), fmaxf(c.z, c.w)), m2);
    }
#pragma unroll
    for (int off = 32; off > 0; off >>= 1) {
        m1 = fmaxf(m1, __shfl_down(m1, off, 64));
        m2 = fmaxf(m2, __shfl_down(m2, off, 64));
    }
    __shared__ float s1[4], s2[4];
    if ((t & 63) == 0) { s1[t >> 6] = m1; s2[t >> 6] = m2; }
    __syncthreads();
    if (t == 0) {
        float a = fmaxf(fmaxf(s1[0], s1[1]), fmaxf(s1[2], s1[3]));
        float c = fmaxf(fmaxf(s2[0], s2[1]), fmaxf(s2[2], s2[3]));
        out[b] = 0.5f * (a + c);              // wsmin holds full d
    }
}

extern "C" void kernel_launch(void* const* d_in, const int* in_sizes, int n_in,
                              void* d_out, int out_size, void* d_ws, size_t ws_size,
                              hipStream_t stream) {
    const float* preds = (const float*)d_in[0];
    const float* gts   = (const float*)d_in[1];
    float* out = (float*)d_out;
    unsigned int* wsmin = (unsigned int*)d_ws;   // 512 KB used

    // 0xFF fill = +inf sentinel for uint atomicMin (all finite d bits smaller)
    hipMemsetAsync(wsmin, 0xFF, (size_t)WSMIN_N * sizeof(unsigned int), stream);

    haus_scan_kernel<<<dim3(NHB * SPLIT, NB, 2), dim3(TPB), 0, stream>>>(
        preds, gts, wsmin);

    haus_final_kernel<<<dim3(NB), dim3(TPB), 0, stream>>>(wsmin, out);
}

// Round 13
// 85.315 us; speedup vs baseline: 1.0643x; 1.0643x over previous
//
#include <hip/hip_runtime.h>
#include <math.h>

// Hausdorff distance, B=16, N=4096, D=3, fp32.
// out[b] = 0.5*(max_gt min_pred d + max_pred min_gt d), d = ||p-q||^2
//
// R13: FUSED directions. R9..R12 scan pinned at ~42us across DPP /
// occupancy / min3 / pairing changes -> per-pipe tuning exhausted.
// Both directions share the pairwise matrix: compute each 32x32 tile
// ONCE, update row-mins (-> loss1, per gt) AND col-mins (-> loss2,
// per pred). All work halves (MFMA 6.8->3.4us, ds_read, staging,
// blocks 2048->1024).
//  - hg folded INTO the MFMA via spare K slots (A k11,k12 = hg hi/lo,
//    B k11,k12 = 1), so D = hg[m] + hp[n] - 2 g.p = full d: col-min
//    needs no per-row add. (Same mechanism as the R9-validated hp-in-K.)
//  - per tile col-min: v_min3 tree over both streams' 32 regs,
//    __shfl_xor(32) cross-half, LDS atomicMin(int) into scol[OPP]
//    (signed-int ordering == float ordering for vals >= -eps; clamped
//    >=0 before the global uint atomicMin merge).
//  - rows: best-reg accumulate over tiles + DPP ror{1,2,4,8} +
//    ds_swizzle xor16 epilogue (R11-validated), no shg add needed.
// LDS: srec 32KB + scol 4KB = 36KB -> 4 blocks/CU; 1024 blocks = one
// resident round of 16 waves/CU.
// C/D (m74/m101, R9..R12-validated): col=lane&31,
// row=(reg&3)+8*(reg>>2)+4*(lane>>5).

#define NPTS 4096
#define NB 16
#define TPB 256
#define WAVES 4
#define GPW 64                    // gts per wave (2 MFMA streams)
#define GPB (WAVES * GPW)         // 256 gts per block
#define NGB (NPTS / GPB)          // 16 gt blocks
#define SPLIT 4
#define OPP (NPTS / SPLIT)        // 1024 preds staged per block
#define TILES (OPP / 32)          // 32 bfrag tiles per wave

#define WSMIN_N (2 * NB * NPTS)

typedef _Float16 h8 __attribute__((ext_vector_type(8)));
typedef float f16v __attribute__((ext_vector_type(16)));

// min with DPP row_ror:N (VALU pipe; rows of 16 lanes, cyclic rotate)
template <int CTRL>
__device__ __forceinline__ float min_dpp(float v) {
    int s = __builtin_amdgcn_update_dpp(0, __float_as_int(v), CTRL, 0xF, 0xF, true);
    return fminf(v, __int_as_float(s));
}

__global__ __launch_bounds__(TPB) void haus_scan_kernel(
        const float* __restrict__ preds, const float* __restrict__ gts,
        unsigned int* __restrict__ wsmin) {
    const int gt  = blockIdx.x & (NGB - 1);   // gt tile index
    const int sp  = blockIdx.x >> 4;          // pred chunk index (NGB==16)
    const int b   = blockIdx.y;
    const int t   = threadIdx.x;
    const int lane = t & 63, w = t >> 6;
    const int l31 = lane & 31, half = lane >> 5;

    const float* gbp = gts   + (size_t)b * NPTS * 3;   // rows (A side)
    const float* pbp = preds + (size_t)b * NPTS * 3;   // cols (B side)

    __shared__ h8 srec[2 * OPP];              // 32KB: [khalf][point] B records
    __shared__ int scol[OPP];                 // 4KB: per-pred col-min (float bits)

    // ---- stage pred chunk: B-form hi/lo records; hp in k9/k10, 1 in k11/k12
#pragma unroll
    for (int i = 0; i < OPP / TPB; ++i) {
        int p = i * TPB + t;
        const float* s = pbp + (size_t)(sp * OPP + p) * 3;
        float x = s[0], y = s[1], z = s[2];
        float hp = fmaf(x, x, fmaf(y, y, z * z));
        _Float16 xh = (_Float16)x, yh = (_Float16)y, zh = (_Float16)z;
        _Float16 xl = (_Float16)(x - (float)xh);
        _Float16 yl = (_Float16)(y - (float)yh);
        _Float16 zl = (_Float16)(z - (float)zh);
        _Float16 hph = (_Float16)hp, hpl = (_Float16)(hp - (float)hph);
        h8 lo, hi;
        lo[0] = xh; lo[1] = yh; lo[2] = zh;       // k0..2: p_hi
        lo[3] = xl; lo[4] = yl; lo[5] = zl;       // k3..5: p_lo
        lo[6] = xh; lo[7] = yh;                   // k6..7: p_hi (x,y)
        hi[0] = zh;                               // k8:    p_hi z
        hi[1] = hph; hi[2] = hpl;                 // k9..10: hp hi/lo
        hi[3] = (_Float16)1; hi[4] = (_Float16)1; // k11..12: 1 (x hg hi/lo)
        hi[5] = (_Float16)0; hi[6] = (_Float16)0; hi[7] = (_Float16)0;
        srec[p] = lo;
        srec[OPP + p] = hi;
        scol[p] = 0x7F800000;                     // +inf (positive -> signed ok)
    }

    // ---- A-frags: two streams of 32 gts; -2g hi/lo + hg hi/lo in k11/k12
    h8 afrag[2];
#pragma unroll
    for (int a = 0; a < 2; ++a) {
        int m = gt * GPB + w * GPW + a * 32 + l31;
        float gx = gbp[m * 3 + 0], gy = gbp[m * 3 + 1], gz = gbp[m * 3 + 2];
        float hg = fmaf(gx, gx, fmaf(gy, gy, gz * gz));
        _Float16 gxh = (_Float16)gx, gyh = (_Float16)gy, gzh = (_Float16)gz;
        _Float16 gxl = (_Float16)(gx - (float)gxh);
        _Float16 gyl = (_Float16)(gy - (float)gyh);
        _Float16 gzl = (_Float16)(gz - (float)gzh);
        _Float16 hgh = (_Float16)hg, hgl = (_Float16)(hg - (float)hgh);
        const _Float16 n2 = (_Float16)(-2.0f);
        h8 f;
        if (half == 0) {                      // k0..7
            f[0] = n2 * gxh; f[1] = n2 * gyh; f[2] = n2 * gzh;
            f[3] = n2 * gxh; f[4] = n2 * gyh; f[5] = n2 * gzh;
            f[6] = n2 * gxl; f[7] = n2 * gyl;
        } else {                              // k8..15
            f[0] = n2 * gzl;                  // k8
            f[1] = (_Float16)1; f[2] = (_Float16)1;   // k9..10 (x hp hi/lo)
            f[3] = hgh; f[4] = hgl;           // k11..12: hg hi/lo (x 1)
            f[5] = (_Float16)0; f[6] = (_Float16)0; f[7] = (_Float16)0;
        }
        afrag[a] = f;
    }

    f16v zc = {};                             // zero C
    float best0[16], best1[16];
#pragma unroll
    for (int r = 0; r < 16; ++r) { best0[r] = INFINITY; best1[r] = INFINITY; }

    __syncthreads();

    const h8* sptr = srec + half * OPP + l31;
#pragma unroll 2
    for (int tt = 0; tt < TILES; ++tt) {
        h8 bfrag = sptr[tt * 32];             // one ds_read_b128, conflict-free
        f16v D0 = __builtin_amdgcn_mfma_f32_32x32x16_f16(afrag[0], bfrag, zc, 0, 0, 0);
        f16v D1 = __builtin_amdgcn_mfma_f32_32x32x16_f16(afrag[1], bfrag, zc, 0, 0, 0);
        // row-min accumulate (rows = gts, fixed per wave)
#pragma unroll
        for (int r = 0; r < 16; ++r) best0[r] = fminf(best0[r], D0[r]);
#pragma unroll
        for (int r = 0; r < 16; ++r) best1[r] = fminf(best1[r], D1[r]);
        // col-min over this tile's 64 rows (both streams), per lane = one col
        float cm = fminf(D0[0], D1[0]);
#pragma unroll
        for (int r = 1; r < 16; ++r)          // v_min3 pattern
            cm = fminf(fminf(cm, D0[r]), D1[r]);
        cm = fminf(cm, __shfl_xor(cm, 32, 64));   // cross the lane halves
        if (half == 0)                        // lanes 0..31: col tt*32+l31
            atomicMin(&scol[tt * 32 + l31], __float_as_int(cm));
    }

    // ---- row epilogue: min over 32 cols (DPP ror + xor16), then atomics
#pragma unroll
    for (int r = 0; r < 16; ++r) {
        float a0 = best0[r], a1 = best1[r];
        a0 = min_dpp<0x121>(a0); a1 = min_dpp<0x121>(a1);   // ror 1
        a0 = min_dpp<0x122>(a0); a1 = min_dpp<0x122>(a1);   // ror 2
        a0 = min_dpp<0x124>(a0); a1 = min_dpp<0x124>(a1);   // ror 4
        a0 = min_dpp<0x128>(a0); a1 = min_dpp<0x128>(a1);   // ror 8
        float s0 = __int_as_float(__builtin_amdgcn_ds_swizzle(__float_as_int(a0), 0x401F));
        float s1 = __int_as_float(__builtin_amdgcn_ds_swizzle(__float_as_int(a1), 0x401F));
        best0[r] = fminf(a0, s0);
        best1[r] = fminf(a1, s1);
    }
    unsigned int* wsrow = wsmin + ((size_t)0 * NB + b) * NPTS + gt * GPB + w * GPW;
    if (l31 == 0) {                           // lanes 0 and 32: disjoint row sets
#pragma unroll
        for (int r = 0; r < 16; ++r) {
            int row = (r & 3) + 8 * (r >> 2) + 4 * half;
            float d0 = fmaxf(best0[r], 0.0f); // D is full d: no hg add
            float d1 = fmaxf(best1[r], 0.0f);
            atomicMin(wsrow + row, __float_as_uint(d0));
            atomicMin(wsrow + 32 + row, __float_as_uint(d1));
        }
    }

    // ---- col merge: scol -> global (after all waves' LDS atomics) ----
    __syncthreads();
    unsigned int* wscol = wsmin + ((size_t)1 * NB + b) * NPTS + sp * OPP;
#pragma unroll
    for (int i = 0; i < OPP / TPB; ++i) {
        int p = i * TPB + t;
        float c = fmaxf(__int_as_float(scol[p]), 0.0f);  // clamp: uint order ok
        atomicMin(wscol + p, __float_as_uint(c));
    }
}

__global__ __launch_bounds__(TPB) void haus_final_kernel(
        const unsigned int* __restrict__ wsmin, float* __restrict__ out) {
    const int b = blockIdx.x;
    const int t = threadIdx.x;
    const float4* w0 = (const float4*)(wsmin + ((size_t)0 * NB + b) * NPTS);
    const float4* w1 = (const float4*)(wsmin + ((size_t)1 * NB + b) * NPTS);
    float m1 = -INFINITY, m2 = -INFINITY;
#pragma unroll
    for (int r = 0; r < NPTS / 4 / TPB; ++r) {   // 4 float4 per thread
        float4 a = w0[r * TPB + t];
        float4 c = w1[r * TPB + t];
        m1 = fmaxf(fmaxf(fmaxf(a.x, a.y), fmaxf(a.z, a.w)), m1);
        m2 = fmaxf(fmaxf(fmaxf(c.x, c.y), fmaxf(c.z, c.w)), m2);
    }
#pragma unroll
    for (int off = 32; off > 0; off >>= 1) {
        m1 = fmaxf(m1, __shfl_down(m1, off, 64));
        m2 = fmaxf(m2, __shfl_down(m2, off, 64));
    }
    __shared__ float s1[4], s2[4];
    if ((t & 63) == 0) { s1[t >> 6] = m1; s2[t >> 6] = m2; }
    __syncthreads();
    if (t == 0) {
        float a = fmaxf(fmaxf(s1[0], s1[1]), fmaxf(s1[2], s1[3]));
        float c = fmaxf(fmaxf(s2[0], s2[1]), fmaxf(s2[2], s2[3]));
        out[b] = 0.5f * (a + c);              // wsmin holds full d both sides
    }
}

extern "C" void kernel_launch(void* const* d_in, const int* in_sizes, int n_in,
                              void* d_out, int out_size, void* d_ws, size_t ws_size,
                              hipStream_t stream) {
    const float* preds = (const float*)d_in[0];
    const float* gts   = (const float*)d_in[1];
    float* out = (float*)d_out;
    unsigned int* wsmin = (unsigned int*)d_ws;   // 512 KB used

    // 0xFF fill = +inf sentinel for uint atomicMin (all finite d bits smaller)
    hipMemsetAsync(wsmin, 0xFF, (size_t)WSMIN_N * sizeof(unsigned int), stream);

    haus_scan_kernel<<<dim3(NGB * SPLIT, NB, 1), dim3(TPB), 0, stream>>>(
        preds, gts, wsmin);

    haus_final_kernel<<<dim3(NB), dim3(TPB), 0, stream>>>(wsmin, out);
}